// Round 12
// baseline (145.665 us; speedup 1.0000x reference)
//
#include <hip/hip_runtime.h>
#include <hip/hip_bf16.h>

namespace {

constexpr int T  = 200;

typedef float f32x4 __attribute__((ext_vector_type(4)));
typedef short bf16x8 __attribute__((ext_vector_type(8)));
typedef unsigned int u32;
typedef u32 u32x4 __attribute__((ext_vector_type(4)));

__device__ __forceinline__ short f2bf(float f) {
  __hip_bfloat16 h = __float2bfloat16(f);
  return __builtin_bit_cast(short, h);
}
__device__ __forceinline__ float bflo2f(u32 u) { return __uint_as_float(u << 16); }
__device__ __forceinline__ float bfhi2f(u32 u) { return __uint_as_float(u & 0xFFFF0000u); }

template <int CTRL>
__device__ __forceinline__ float dpp_add(float x) {
  int y = __builtin_amdgcn_update_dpp(0, __float_as_int(x), CTRL, 0xF, 0xF, true);
  return x + __int_as_float(y);
}
__device__ __forceinline__ float sum16(float x) {
  x = dpp_add<0x121>(x); x = dpp_add<0x122>(x);
  x = dpp_add<0x124>(x); x = dpp_add<0x128>(x);
  return x;
}

// LDS floats: M 8192 (32KB bf16 128x128, slot ^= (d&15)); u2[2][128]; outl[4][128]; red[8]
constexpr int OFF_U2   = 8192;
constexpr int OFF_OUTL = 8448;
constexpr int OFF_RED  = 8960;
constexpr int SMEM_F   = 8968;

__global__ void pre_kernel(const float* __restrict__ w1, u32* __restrict__ MD,
                           float* __restrict__ sTf) {
  int idx = blockIdx.x * 256 + threadIdx.x;  // 64 x 256 = 16384
  int d = idx >> 7, f = idx & 127;
  const float* r = w1 + (size_t)d * 512;
  u32 lo = (unsigned short)f2bf(r[128 + f] - r[256 + f]);  // Bm - C
  u32 hi = (unsigned short)f2bf(r[384 + f]);               // Dm
  MD[idx] = lo | (hi << 16);
  sTf[(size_t)f * 128 + d] = r[f] + r[256 + f];            // (A+C)^T, f-major
}

__global__ void preU_kernel(const float* __restrict__ qg, const float* __restrict__ sTf,
                            const float* __restrict__ b1g, float* __restrict__ uall) {
  __shared__ float qs[128];
  int b = blockIdx.x, d = threadIdx.x;
  qs[d] = qg[(size_t)b * 128 + d];
  __syncthreads();
  float acc = b1g[d];
  #pragma unroll 16
  for (int f = 0; f < 128; ++f) acc += qs[f] * sTf[(size_t)f * 128 + d];
  uall[(size_t)b * 128 + d] = acc;
}

__device__ __forceinline__ bool mask_at(const void* m, int mcode, size_t i) {
  if (mcode == 0) return ((const int*)m)[i] != 0;
  if (mcode == 1) return ((const unsigned char*)m)[i] != 0;
  return ((const float*)m)[i] != 0.f;
}

__global__ __launch_bounds__(256, 4) void din_kernel(
    const float* __restrict__ qg, const float* __restrict__ keysg,
    const void* __restrict__ maskg, const float* __restrict__ w1g,
    const float* __restrict__ b1g, const float* __restrict__ pag,
    const float* __restrict__ w2g, const float* __restrict__ b2g,
    const u32* __restrict__ MD, const float* __restrict__ uall,
    int mode, float* __restrict__ outg) {
  __shared__ __align__(16) float smem[SMEM_F];
  float* u2   = smem + OFF_U2;
  float* outl = smem + OFF_OUTL;
  float* red  = smem + OFF_RED;

  const int tid  = threadIdx.x;
  const int b    = blockIdx.x;
  const int wid  = tid >> 6;         // 0..3
  const int lane = tid & 63;
  const int lrow = (lane >> 4) & 3;
  const int lcol = lane & 15;

  const float* qb    = qg + (size_t)b * 128;
  const float* keysB = keysg + (size_t)b * T * 128;

  // ---- mask dtype detector (wave-uniform, no barrier) ----
  int mcode;
  {
    unsigned v = ((const unsigned*)maskg)[lane];
    unsigned c0 = v & 255u, c1 = (v >> 8) & 255u, c2 = (v >> 16) & 255u, c3 = v >> 24;
    bool weird = (c0 == 0x80u) | (c0 == 0x3Fu) | (c1 == 0x80u) | (c1 == 0x3Fu) |
                 (c2 == 0x80u) | (c2 == 0x3Fu) | (c3 == 0x80u) | (c3 == 0x3Fu);
    bool nz = (v & 0xFFFFFF00u) != 0u;
    unsigned long long bw = __ballot(weird);
    unsigned long long bn = __ballot(nz);
    mcode = bw ? 2 : (bn ? 1 : 0);  // 2=f32, 1=byte, 0=int32
  }

  const float pa  = pag[0];
  const float b2v = b2g[0];

  // ---- K-tile load into fp32 regs (A-frag: lane row=lcol, f=ks*32+lrow*8+j) ----
  f32x4 ka0[4], ka1[4], kb0[4], kb1[4];
  #define LOADK(K0, K1, TILE)                                        \
    do {                                                             \
      int trow_ = (TILE) * 16 + lcol;                                \
      int trc_  = trow_ < T ? trow_ : T - 1;                         \
      const float* kr_ = keysB + (size_t)trc_ * 128 + lrow * 8;      \
      _Pragma("unroll")                                              \
      for (int ks = 0; ks < 4; ++ks) {                               \
        K0[ks] = *(const f32x4*)(kr_ + ks * 32);                     \
        K1[ks] = *(const f32x4*)(kr_ + ks * 32 + 4);                 \
      }                                                              \
    } while (0)

  LOADK(ka0, ka1, wid);      // tiles wid and wid+4 prefetched through prologue
  LOADK(kb0, kb1, wid + 4);

  // ---- mask -> 4 wave-uniform u64 bitmasks (latency overlaps M build) ----
  unsigned long long mw0, mw1, mw2, mw3;
  {
    size_t base = (size_t)b * T;
    bool v0 = mask_at(maskg, mcode, base + lane);
    bool v1 = mask_at(maskg, mcode, base + 64 + lane);
    bool v2 = mask_at(maskg, mcode, base + 128 + lane);
    bool v3 = (192 + lane < T) ? mask_at(maskg, mcode, base + 192 + lane) : false;
    mw0 = __ballot(v0); mw1 = __ballot(v1); mw2 = __ballot(v2); mw3 = __ballot(v3);
  }

  // ---- build M in LDS: M[d][f] = (Bm-C)[d][f] + Dm[d][f]*q[f], bf16, swizzled ----
  if (mode >= 1) {
    #pragma unroll
    for (int i = 0; i < 8; ++i) {
      int e = i * 2048 + tid * 8;
      int d = e >> 7, f = e & 127;
      u32x4 A = *(const u32x4*)(MD + e);
      u32x4 B = *(const u32x4*)(MD + e + 4);
      f32x4 q0 = *(const f32x4*)(qb + f), q1 = *(const f32x4*)(qb + f + 4);
      bf16x8 v;
      v[0] = f2bf(bflo2f(A.x) + bfhi2f(A.x) * q0.x);
      v[1] = f2bf(bflo2f(A.y) + bfhi2f(A.y) * q0.y);
      v[2] = f2bf(bflo2f(A.z) + bfhi2f(A.z) * q0.z);
      v[3] = f2bf(bflo2f(A.w) + bfhi2f(A.w) * q0.w);
      v[4] = f2bf(bflo2f(B.x) + bfhi2f(B.x) * q1.x);
      v[5] = f2bf(bflo2f(B.y) + bfhi2f(B.y) * q1.y);
      v[6] = f2bf(bflo2f(B.z) + bfhi2f(B.z) * q1.z);
      v[7] = f2bf(bflo2f(B.w) + bfhi2f(B.w) * q1.w);
      int slot = (f >> 3) ^ (d & 15);
      *(bf16x8*)((char*)smem + d * 256 + slot * 16) = v;
    }
  } else {
    #pragma unroll
    for (int i = 0; i < 8; ++i) {
      int e = i * 2048 + tid * 8;
      int d = e >> 7, f = e & 127;
      const float* r = w1g + (size_t)d * 512;
      f32x4 bB0 = *(const f32x4*)(r + 128 + f), bB1 = *(const f32x4*)(r + 128 + f + 4);
      f32x4 cC0 = *(const f32x4*)(r + 256 + f), cC1 = *(const f32x4*)(r + 256 + f + 4);
      f32x4 dd0 = *(const f32x4*)(r + 384 + f), dd1 = *(const f32x4*)(r + 384 + f + 4);
      f32x4 q0 = *(const f32x4*)(qb + f), q1 = *(const f32x4*)(qb + f + 4);
      bf16x8 v;
      v[0] = f2bf(bB0.x - cC0.x + dd0.x * q0.x);
      v[1] = f2bf(bB0.y - cC0.y + dd0.y * q0.y);
      v[2] = f2bf(bB0.z - cC0.z + dd0.z * q0.z);
      v[3] = f2bf(bB0.w - cC0.w + dd0.w * q0.w);
      v[4] = f2bf(bB1.x - cC1.x + dd1.x * q1.x);
      v[5] = f2bf(bB1.y - cC1.y + dd1.y * q1.y);
      v[6] = f2bf(bB1.z - cC1.z + dd1.z * q1.z);
      v[7] = f2bf(bB1.w - cC1.w + dd1.w * q1.w);
      int slot = (f >> 3) ^ (d & 15);
      *(bf16x8*)((char*)smem + d * 256 + slot * 16) = v;
    }
  }

  // ---- u: from preU (mode 2) or in-kernel GEMV fallback ----
  if (mode == 2) {
    if (tid < 128) u2[tid] = uall[(size_t)b * 128 + tid];
    else if (tid < 256) u2[tid] = 0.f;   // u2[128..255] zeroed; loop sums both
  } else {
    int d = tid & 127, fh = tid >> 7;
    const float* arow = w1g + (size_t)d * 512 + fh * 64;
    const float* crow = arow + 256;
    const float* qh   = qb + fh * 64;
    float acc = 0.f;
    #pragma unroll
    for (int i = 0; i < 16; ++i) {
      f32x4 qv = *(const f32x4*)(qh + i * 4);
      f32x4 av = *(const f32x4*)(arow + i * 4);
      f32x4 cv = *(const f32x4*)(crow + i * 4);
      acc += qv.x * (av.x + cv.x) + qv.y * (av.y + cv.y) +
             qv.z * (av.z + cv.z) + qv.w * (av.w + cv.w);
    }
    if (fh == 0) acc += b1g[d];
    u2[fh * 128 + d] = acc;
  }

  __syncthreads();  // barrier 1: M + u2 ready

  // hoist per-lane w2 for its 8 d-columns
  float w2w[8];
  #pragma unroll
  for (int dt = 0; dt < 8; ++dt) w2w[dt] = w2g[dt * 16 + lcol];

  float m_w = -1e9f, den_w = 0.f;
  float accpv[32];
  #pragma unroll
  for (int i = 0; i < 32; ++i) accpv[i] = 0.f;

  #define COMPUTE(TILE, K0, K1)                                              \
    do {                                                                     \
      const int tile_ = (TILE);                                              \
      bf16x8 af[4];                                                          \
      _Pragma("unroll")                                                      \
      for (int ks = 0; ks < 4; ++ks) {                                       \
        af[ks][0] = f2bf(K0[ks].x); af[ks][1] = f2bf(K0[ks].y);              \
        af[ks][2] = f2bf(K0[ks].z); af[ks][3] = f2bf(K0[ks].w);              \
        af[ks][4] = f2bf(K1[ks].x); af[ks][5] = f2bf(K1[ks].y);              \
        af[ks][6] = f2bf(K1[ks].z); af[ks][7] = f2bf(K1[ks].w);              \
      }                                                                      \
      float sj[4] = {0.f, 0.f, 0.f, 0.f};                                    \
      __builtin_amdgcn_s_setprio(1);                                         \
      _Pragma("unroll")                                                      \
      for (int dt = 0; dt < 8; ++dt) {                                       \
        int d_ = dt * 16 + lcol;                                             \
        float u_d = u2[d_] + u2[128 + d_];                                   \
        f32x4 acc = {u_d, u_d, u_d, u_d};   /* u folded into C-in */         \
        _Pragma("unroll")                                                    \
        for (int ks = 0; ks < 4; ++ks) {                                     \
          bf16x8 bfv = *(const bf16x8*)((const char*)smem + d_ * 256 +       \
                                        (((ks * 4 + lrow) ^ (d_ & 15)) << 4)); \
          acc = __builtin_amdgcn_mfma_f32_16x16x32_bf16(af[ks], bfv, acc, 0, 0, 0); \
        }                                                                    \
        float w2d = w2w[dt];                                                 \
        _Pragma("unroll")                                                    \
        for (int j = 0; j < 4; ++j) {                                        \
          float h = acc[j];                                                  \
          h = (h >= 0.f) ? h : pa * h;                                       \
          sj[j] += h * w2d;                                                  \
        }                                                                    \
      }                                                                      \
      __builtin_amdgcn_s_setprio(0);                                         \
      _Pragma("unroll")                                                      \
      for (int j = 0; j < 4; ++j) sj[j] = sum16(sj[j]);                      \
      unsigned long long mword = tile_ < 4 ? mw0 : tile_ < 8 ? mw1           \
                                 : tile_ < 12 ? mw2 : mw3;                   \
      float mt = -1e30f;                                                     \
      _Pragma("unroll")                                                      \
      for (int j = 0; j < 4; ++j) {                                          \
        int bitp = ((tile_ & 3) << 4) + lrow * 4 + j;                        \
        bool valid = (mword >> bitp) & 1ull;                                 \
        sj[j] = valid ? (sj[j] + b2v) : -1e30f;                              \
        mt = fmaxf(mt, sj[j]);                                               \
      }                                                                      \
      mt = fmaxf(mt, __shfl_xor(mt, 16));                                    \
      mt = fmaxf(mt, __shfl_xor(mt, 32));                                    \
      if (mt > m_w + 8.f) {  /* defer-max: rescale only on big growth */     \
        float sc = __expf(m_w - mt);                                         \
        den_w *= sc;                                                         \
        _Pragma("unroll")                                                    \
        for (int i = 0; i < 32; ++i) accpv[i] *= sc;                         \
        m_w = mt;                                                            \
      }                                                                      \
      float wj[4], dsum = 0.f;                                               \
      _Pragma("unroll")                                                      \
      for (int j = 0; j < 4; ++j) { wj[j] = __expf(sj[j] - m_w); dsum += wj[j]; } \
      dsum += __shfl_xor(dsum, 16);                                          \
      dsum += __shfl_xor(dsum, 32);                                          \
      den_w += dsum;                                                         \
      float tmp = (lcol & 2) ? ((lcol & 1) ? wj[3] : wj[2])                  \
                             : ((lcol & 1) ? wj[1] : wj[0]);                 \
      float wtr = __shfl(tmp, ((lcol >> 2) << 4) | (lcol & 3), 64);          \
      _Pragma("unroll")                                                      \
      for (int ks = 0; ks < 4; ++ks) {                                       \
        accpv[ks * 8 + 0] += wtr * K0[ks].x;                                 \
        accpv[ks * 8 + 1] += wtr * K0[ks].y;                                 \
        accpv[ks * 8 + 2] += wtr * K0[ks].z;                                 \
        accpv[ks * 8 + 3] += wtr * K0[ks].w;                                 \
        accpv[ks * 8 + 4] += wtr * K1[ks].x;                                 \
        accpv[ks * 8 + 5] += wtr * K1[ks].y;                                 \
        accpv[ks * 8 + 6] += wtr * K1[ks].z;                                 \
        accpv[ks * 8 + 7] += wtr * K1[ks].w;                                 \
      }                                                                      \
    } while (0)

  // tiles: wid, wid+4, wid+8 for all waves; tile 12 only for wave 0
  COMPUTE(wid, ka0, ka1);
  LOADK(ka0, ka1, wid + 8);          // overlaps next compute
  COMPUTE(wid + 4, kb0, kb1);
  if (wid == 0) LOADK(kb0, kb1, 12);
  COMPUTE(wid + 8, ka0, ka1);
  if (wid == 0) COMPUTE(12, kb0, kb1);

  // ---- fold rows across the 16-lane group (DPP); write per-wave partials ----
  #pragma unroll
  for (int i = 0; i < 32; ++i) accpv[i] = sum16(accpv[i]);
  if (lcol == 0) {
    #pragma unroll
    for (int ks = 0; ks < 4; ++ks) {
      f32x4 a = {accpv[ks * 8 + 0], accpv[ks * 8 + 1], accpv[ks * 8 + 2], accpv[ks * 8 + 3]};
      f32x4 c = {accpv[ks * 8 + 4], accpv[ks * 8 + 5], accpv[ks * 8 + 6], accpv[ks * 8 + 7]};
      *(f32x4*)(outl + wid * 128 + ks * 32 + lrow * 8)     = a;
      *(f32x4*)(outl + wid * 128 + ks * 32 + lrow * 8 + 4) = c;
    }
  }
  if (lane == 0) { red[wid] = m_w; red[4 + wid] = den_w; }

  __syncthreads();  // barrier 2: partials ready

  if (tid < 128) {
    float M = fmaxf(fmaxf(red[0], red[1]), fmaxf(red[2], red[3]));
    float den = 0.f, o = 0.f;
    #pragma unroll
    for (int w = 0; w < 4; ++w) {
      float scw = __expf(red[w] - M);
      den += red[4 + w] * scw;
      o   += outl[w * 128 + tid] * scw;
    }
    float inv = (den > 0.f) ? 1.0f / den : 0.f;
    outg[(size_t)b * 128 + tid] = o * inv;
  }
  #undef COMPUTE
  #undef LOADK
}

}  // namespace

extern "C" void kernel_launch(void* const* d_in, const int* in_sizes, int n_in,
                              void* d_out, int out_size, void* d_ws, size_t ws_size,
                              hipStream_t stream) {
  (void)in_sizes; (void)n_in; (void)out_size;
  const float* q    = (const float*)d_in[0];
  const float* keys = (const float*)d_in[1];
  const void*  mask = d_in[2];
  const float* w1   = (const float*)d_in[3];
  const float* b1   = (const float*)d_in[4];
  const float* pa   = (const float*)d_in[5];
  const float* w2   = (const float*)d_in[6];
  const float* b2   = (const float*)d_in[7];
  float* out = (float*)d_out;

  u32* MD     = (u32*)d_ws;                       // 64 KB packed (Bm-C | Dm)
  float* sTf  = (float*)((char*)d_ws + 65536);    // 64 KB (A+C) f-major
  float* uall = (float*)((char*)d_ws + 131072);   // 1 MB u[B][128]
  int mode = 0;
  if (ws_size >= (size_t)131072 + (size_t)2048 * 128 * 4) mode = 2;
  else if (ws_size >= (size_t)131072)                     mode = 1;

  if (mode >= 1) pre_kernel<<<64, 256, 0, stream>>>(w1, MD, sTf);
  if (mode == 2) preU_kernel<<<2048, 128, 0, stream>>>(q, sTf, b1, uall);
  din_kernel<<<2048, 256, 0, stream>>>(q, keys, mask, w1, b1, pa, w2, b2,
                                       MD, uall, mode, out);
}

// Round 13
// 74.209 us; speedup vs baseline: 1.9629x; 1.9629x over previous
//
#include <hip/hip_runtime.h>
#include <hip/hip_bf16.h>

namespace {

constexpr int T  = 200;

typedef float f32x4 __attribute__((ext_vector_type(4)));
typedef short bf16x8 __attribute__((ext_vector_type(8)));
typedef unsigned int u32;
typedef u32 u32x4 __attribute__((ext_vector_type(4)));

__device__ __forceinline__ short f2bf(float f) {
  __hip_bfloat16 h = __float2bfloat16(f);
  return __builtin_bit_cast(short, h);
}
__device__ __forceinline__ float bflo2f(u32 u) { return __uint_as_float(u << 16); }
__device__ __forceinline__ float bfhi2f(u32 u) { return __uint_as_float(u & 0xFFFF0000u); }

template <int CTRL>
__device__ __forceinline__ float dpp_add(float x) {
  int y = __builtin_amdgcn_update_dpp(0, __float_as_int(x), CTRL, 0xF, 0xF, true);
  return x + __int_as_float(y);
}
__device__ __forceinline__ float sum16(float x) {
  x = dpp_add<0x121>(x); x = dpp_add<0x122>(x);
  x = dpp_add<0x124>(x); x = dpp_add<0x128>(x);
  return x;
}

// LDS floats: M 8192 (32KB bf16 128x128, slot ^= (d&15)); u2[2][128]; outl[4][128]; red[8]
constexpr int OFF_U2   = 8192;
constexpr int OFF_OUTL = 8448;
constexpr int OFF_RED  = 8960;
constexpr int SMEM_F   = 8968;

__global__ void pre_kernel(const float* __restrict__ w1, u32* __restrict__ MD,
                           float* __restrict__ sTf) {
  int idx = blockIdx.x * 256 + threadIdx.x;  // 64 x 256 = 16384
  int d = idx >> 7, f = idx & 127;
  const float* r = w1 + (size_t)d * 512;
  u32 lo = (unsigned short)f2bf(r[128 + f] - r[256 + f]);  // Bm - C
  u32 hi = (unsigned short)f2bf(r[384 + f]);               // Dm
  MD[idx] = lo | (hi << 16);
  sTf[(size_t)f * 128 + d] = r[f] + r[256 + f];            // (A+C)^T, f-major
}

__global__ void preU_kernel(const float* __restrict__ qg, const float* __restrict__ sTf,
                            const float* __restrict__ b1g, float* __restrict__ uall) {
  __shared__ float qs[128];
  int b = blockIdx.x, d = threadIdx.x;
  qs[d] = qg[(size_t)b * 128 + d];
  __syncthreads();
  float acc = b1g[d];
  #pragma unroll 16
  for (int f = 0; f < 128; ++f) acc += qs[f] * sTf[(size_t)f * 128 + d];
  uall[(size_t)b * 128 + d] = acc;
}

__device__ __forceinline__ bool mask_at(const void* m, int mcode, size_t i) {
  if (mcode == 0) return ((const int*)m)[i] != 0;
  if (mcode == 1) return ((const unsigned char*)m)[i] != 0;
  return ((const float*)m)[i] != 0.f;
}

__global__ __launch_bounds__(256, 2) void din_kernel(
    const float* __restrict__ qg, const float* __restrict__ keysg,
    const void* __restrict__ maskg, const float* __restrict__ w1g,
    const float* __restrict__ b1g, const float* __restrict__ pag,
    const float* __restrict__ w2g, const float* __restrict__ b2g,
    const u32* __restrict__ MD, const float* __restrict__ uall,
    int mode, float* __restrict__ outg) {
  __shared__ __align__(16) float smem[SMEM_F];
  float* u2   = smem + OFF_U2;
  float* outl = smem + OFF_OUTL;
  float* red  = smem + OFF_RED;

  const int tid  = threadIdx.x;
  const int b    = blockIdx.x;
  const int wid  = tid >> 6;         // 0..3
  const int lane = tid & 63;
  const int lrow = (lane >> 4) & 3;
  const int lcol = lane & 15;

  const float* qb    = qg + (size_t)b * 128;
  const float* keysB = keysg + (size_t)b * T * 128;

  // ---- mask dtype detector (wave-uniform, no barrier) ----
  int mcode;
  {
    unsigned v = ((const unsigned*)maskg)[lane];
    unsigned c0 = v & 255u, c1 = (v >> 8) & 255u, c2 = (v >> 16) & 255u, c3 = v >> 24;
    bool weird = (c0 == 0x80u) | (c0 == 0x3Fu) | (c1 == 0x80u) | (c1 == 0x3Fu) |
                 (c2 == 0x80u) | (c2 == 0x3Fu) | (c3 == 0x80u) | (c3 == 0x3Fu);
    bool nz = (v & 0xFFFFFF00u) != 0u;
    unsigned long long bw = __ballot(weird);
    unsigned long long bn = __ballot(nz);
    mcode = bw ? 2 : (bn ? 1 : 0);  // 2=f32, 1=byte, 0=int32
  }

  const float pa  = pag[0];
  const float b2v = b2g[0];

  // ---- K-tile load into fp32 regs (A-frag: lane row=lcol, f=ks*32+lrow*8+j) ----
  f32x4 ka0[4], ka1[4], kb0[4], kb1[4];
  #define LOADK(K0, K1, TILE)                                        \
    do {                                                             \
      int trow_ = (TILE) * 16 + lcol;                                \
      int trc_  = trow_ < T ? trow_ : T - 1;                         \
      const float* kr_ = keysB + (size_t)trc_ * 128 + lrow * 8;      \
      _Pragma("unroll")                                              \
      for (int ks = 0; ks < 4; ++ks) {                               \
        K0[ks] = *(const f32x4*)(kr_ + ks * 32);                     \
        K1[ks] = *(const f32x4*)(kr_ + ks * 32 + 4);                 \
      }                                                              \
    } while (0)

  LOADK(ka0, ka1, wid);      // tiles wid and wid+4 prefetched through prologue
  LOADK(kb0, kb1, wid + 4);

  // ---- mask -> 4 wave-uniform u64 bitmasks (latency overlaps M build) ----
  unsigned long long mw0, mw1, mw2, mw3;
  {
    size_t base = (size_t)b * T;
    bool v0 = mask_at(maskg, mcode, base + lane);
    bool v1 = mask_at(maskg, mcode, base + 64 + lane);
    bool v2 = mask_at(maskg, mcode, base + 128 + lane);
    bool v3 = (192 + lane < T) ? mask_at(maskg, mcode, base + 192 + lane) : false;
    mw0 = __ballot(v0); mw1 = __ballot(v1); mw2 = __ballot(v2); mw3 = __ballot(v3);
  }

  // ---- build M in LDS: M[d][f] = (Bm-C)[d][f] + Dm[d][f]*q[f], bf16, swizzled ----
  if (mode >= 1) {
    #pragma unroll
    for (int i = 0; i < 8; ++i) {
      int e = i * 2048 + tid * 8;
      int d = e >> 7, f = e & 127;
      u32x4 A = *(const u32x4*)(MD + e);
      u32x4 B = *(const u32x4*)(MD + e + 4);
      f32x4 q0 = *(const f32x4*)(qb + f), q1 = *(const f32x4*)(qb + f + 4);
      bf16x8 v;
      v[0] = f2bf(bflo2f(A.x) + bfhi2f(A.x) * q0.x);
      v[1] = f2bf(bflo2f(A.y) + bfhi2f(A.y) * q0.y);
      v[2] = f2bf(bflo2f(A.z) + bfhi2f(A.z) * q0.z);
      v[3] = f2bf(bflo2f(A.w) + bfhi2f(A.w) * q0.w);
      v[4] = f2bf(bflo2f(B.x) + bfhi2f(B.x) * q1.x);
      v[5] = f2bf(bflo2f(B.y) + bfhi2f(B.y) * q1.y);
      v[6] = f2bf(bflo2f(B.z) + bfhi2f(B.z) * q1.z);
      v[7] = f2bf(bflo2f(B.w) + bfhi2f(B.w) * q1.w);
      int slot = (f >> 3) ^ (d & 15);
      *(bf16x8*)((char*)smem + d * 256 + slot * 16) = v;
    }
  } else {
    #pragma unroll
    for (int i = 0; i < 8; ++i) {
      int e = i * 2048 + tid * 8;
      int d = e >> 7, f = e & 127;
      const float* r = w1g + (size_t)d * 512;
      f32x4 bB0 = *(const f32x4*)(r + 128 + f), bB1 = *(const f32x4*)(r + 128 + f + 4);
      f32x4 cC0 = *(const f32x4*)(r + 256 + f), cC1 = *(const f32x4*)(r + 256 + f + 4);
      f32x4 dd0 = *(const f32x4*)(r + 384 + f), dd1 = *(const f32x4*)(r + 384 + f + 4);
      f32x4 q0 = *(const f32x4*)(qb + f), q1 = *(const f32x4*)(qb + f + 4);
      bf16x8 v;
      v[0] = f2bf(bB0.x - cC0.x + dd0.x * q0.x);
      v[1] = f2bf(bB0.y - cC0.y + dd0.y * q0.y);
      v[2] = f2bf(bB0.z - cC0.z + dd0.z * q0.z);
      v[3] = f2bf(bB0.w - cC0.w + dd0.w * q0.w);
      v[4] = f2bf(bB1.x - cC1.x + dd1.x * q1.x);
      v[5] = f2bf(bB1.y - cC1.y + dd1.y * q1.y);
      v[6] = f2bf(bB1.z - cC1.z + dd1.z * q1.z);
      v[7] = f2bf(bB1.w - cC1.w + dd1.w * q1.w);
      int slot = (f >> 3) ^ (d & 15);
      *(bf16x8*)((char*)smem + d * 256 + slot * 16) = v;
    }
  }

  // ---- u: from preU (mode 2) or in-kernel GEMV fallback ----
  if (mode == 2) {
    if (tid < 128) u2[tid] = uall[(size_t)b * 128 + tid];
    else if (tid < 256) u2[tid] = 0.f;   // u2[128..255] zeroed; loop sums both
  } else {
    int d = tid & 127, fh = tid >> 7;
    const float* arow = w1g + (size_t)d * 512 + fh * 64;
    const float* crow = arow + 256;
    const float* qh   = qb + fh * 64;
    float acc = 0.f;
    #pragma unroll
    for (int i = 0; i < 16; ++i) {
      f32x4 qv = *(const f32x4*)(qh + i * 4);
      f32x4 av = *(const f32x4*)(arow + i * 4);
      f32x4 cv = *(const f32x4*)(crow + i * 4);
      acc += qv.x * (av.x + cv.x) + qv.y * (av.y + cv.y) +
             qv.z * (av.z + cv.z) + qv.w * (av.w + cv.w);
    }
    if (fh == 0) acc += b1g[d];
    u2[fh * 128 + d] = acc;
  }

  __syncthreads();  // barrier 1: M + u2 ready

  // hoist per-lane w2 for its 8 d-columns
  float w2w[8];
  #pragma unroll
  for (int dt = 0; dt < 8; ++dt) w2w[dt] = w2g[dt * 16 + lcol];

  float m_w = -1e9f, den_w = 0.f;
  float accpv[32];
  #pragma unroll
  for (int i = 0; i < 32; ++i) accpv[i] = 0.f;

  #define COMPUTE(TILE, K0, K1)                                              \
    do {                                                                     \
      const int tile_ = (TILE);                                              \
      bf16x8 af[4];                                                          \
      _Pragma("unroll")                                                      \
      for (int ks = 0; ks < 4; ++ks) {                                       \
        af[ks][0] = f2bf(K0[ks].x); af[ks][1] = f2bf(K0[ks].y);              \
        af[ks][2] = f2bf(K0[ks].z); af[ks][3] = f2bf(K0[ks].w);              \
        af[ks][4] = f2bf(K1[ks].x); af[ks][5] = f2bf(K1[ks].y);              \
        af[ks][6] = f2bf(K1[ks].z); af[ks][7] = f2bf(K1[ks].w);              \
      }                                                                      \
      float sj[4] = {0.f, 0.f, 0.f, 0.f};                                    \
      __builtin_amdgcn_s_setprio(1);                                         \
      _Pragma("unroll")                                                      \
      for (int dt = 0; dt < 8; ++dt) {                                       \
        int d_ = dt * 16 + lcol;                                             \
        float u_d = u2[d_] + u2[128 + d_];                                   \
        f32x4 acc = {u_d, u_d, u_d, u_d};   /* u folded into C-in */         \
        _Pragma("unroll")                                                    \
        for (int ks = 0; ks < 4; ++ks) {                                     \
          bf16x8 bfv = *(const bf16x8*)((const char*)smem + d_ * 256 +       \
                                        (((ks * 4 + lrow) ^ (d_ & 15)) << 4)); \
          acc = __builtin_amdgcn_mfma_f32_16x16x32_bf16(af[ks], bfv, acc, 0, 0, 0); \
        }                                                                    \
        float w2d = w2w[dt];                                                 \
        _Pragma("unroll")                                                    \
        for (int j = 0; j < 4; ++j) {                                        \
          float h = acc[j];                                                  \
          h = (h >= 0.f) ? h : pa * h;                                       \
          sj[j] += h * w2d;                                                  \
        }                                                                    \
      }                                                                      \
      __builtin_amdgcn_s_setprio(0);                                         \
      _Pragma("unroll")                                                      \
      for (int j = 0; j < 4; ++j) sj[j] = sum16(sj[j]);                      \
      unsigned long long mword = tile_ < 4 ? mw0 : tile_ < 8 ? mw1           \
                                 : tile_ < 12 ? mw2 : mw3;                   \
      float mt = -1e30f;                                                     \
      _Pragma("unroll")                                                      \
      for (int j = 0; j < 4; ++j) {                                          \
        int bitp = ((tile_ & 3) << 4) + lrow * 4 + j;                        \
        bool valid = (mword >> bitp) & 1ull;                                 \
        sj[j] = valid ? (sj[j] + b2v) : -1e30f;                              \
        mt = fmaxf(mt, sj[j]);                                               \
      }                                                                      \
      mt = fmaxf(mt, __shfl_xor(mt, 16));                                    \
      mt = fmaxf(mt, __shfl_xor(mt, 32));                                    \
      if (mt > m_w + 8.f) {  /* defer-max: rescale only on big growth */     \
        float sc = __expf(m_w - mt);                                         \
        den_w *= sc;                                                         \
        _Pragma("unroll")                                                    \
        for (int i = 0; i < 32; ++i) accpv[i] *= sc;                         \
        m_w = mt;                                                            \
      }                                                                      \
      float wj[4], dsum = 0.f;                                               \
      _Pragma("unroll")                                                      \
      for (int j = 0; j < 4; ++j) { wj[j] = __expf(sj[j] - m_w); dsum += wj[j]; } \
      dsum += __shfl_xor(dsum, 16);                                          \
      dsum += __shfl_xor(dsum, 32);                                          \
      den_w += dsum;                                                         \
      float tmp = (lcol & 2) ? ((lcol & 1) ? wj[3] : wj[2])                  \
                             : ((lcol & 1) ? wj[1] : wj[0]);                 \
      float wtr = __shfl(tmp, ((lcol >> 2) << 4) | (lcol & 3), 64);          \
      _Pragma("unroll")                                                      \
      for (int ks = 0; ks < 4; ++ks) {                                       \
        accpv[ks * 8 + 0] += wtr * K0[ks].x;                                 \
        accpv[ks * 8 + 1] += wtr * K0[ks].y;                                 \
        accpv[ks * 8 + 2] += wtr * K0[ks].z;                                 \
        accpv[ks * 8 + 3] += wtr * K0[ks].w;                                 \
        accpv[ks * 8 + 4] += wtr * K1[ks].x;                                 \
        accpv[ks * 8 + 5] += wtr * K1[ks].y;                                 \
        accpv[ks * 8 + 6] += wtr * K1[ks].z;                                 \
        accpv[ks * 8 + 7] += wtr * K1[ks].w;                                 \
      }                                                                      \
    } while (0)

  // tiles: wid, wid+4, wid+8 for all waves; tile 12 only for wave 0
  COMPUTE(wid, ka0, ka1);
  LOADK(ka0, ka1, wid + 8);          // overlaps next compute
  COMPUTE(wid + 4, kb0, kb1);
  if (wid == 0) LOADK(kb0, kb1, 12);
  COMPUTE(wid + 8, ka0, ka1);
  if (wid == 0) COMPUTE(12, kb0, kb1);

  // ---- fold rows across the 16-lane group (DPP); write per-wave partials ----
  #pragma unroll
  for (int i = 0; i < 32; ++i) accpv[i] = sum16(accpv[i]);
  if (lcol == 0) {
    #pragma unroll
    for (int ks = 0; ks < 4; ++ks) {
      f32x4 a = {accpv[ks * 8 + 0], accpv[ks * 8 + 1], accpv[ks * 8 + 2], accpv[ks * 8 + 3]};
      f32x4 c = {accpv[ks * 8 + 4], accpv[ks * 8 + 5], accpv[ks * 8 + 6], accpv[ks * 8 + 7]};
      *(f32x4*)(outl + wid * 128 + ks * 32 + lrow * 8)     = a;
      *(f32x4*)(outl + wid * 128 + ks * 32 + lrow * 8 + 4) = c;
    }
  }
  if (lane == 0) { red[wid] = m_w; red[4 + wid] = den_w; }

  __syncthreads();  // barrier 2: partials ready

  if (tid < 128) {
    float M = fmaxf(fmaxf(red[0], red[1]), fmaxf(red[2], red[3]));
    float den = 0.f, o = 0.f;
    #pragma unroll
    for (int w = 0; w < 4; ++w) {
      float scw = __expf(red[w] - M);
      den += red[4 + w] * scw;
      o   += outl[w * 128 + tid] * scw;
    }
    float inv = (den > 0.f) ? 1.0f / den : 0.f;
    outg[(size_t)b * 128 + tid] = o * inv;
  }
  #undef COMPUTE
  #undef LOADK
}

}  // namespace

extern "C" void kernel_launch(void* const* d_in, const int* in_sizes, int n_in,
                              void* d_out, int out_size, void* d_ws, size_t ws_size,
                              hipStream_t stream) {
  (void)in_sizes; (void)n_in; (void)out_size;
  const float* q    = (const float*)d_in[0];
  const float* keys = (const float*)d_in[1];
  const void*  mask = d_in[2];
  const float* w1   = (const float*)d_in[3];
  const float* b1   = (const float*)d_in[4];
  const float* pa   = (const float*)d_in[5];
  const float* w2   = (const float*)d_in[6];
  const float* b2   = (const float*)d_in[7];
  float* out = (float*)d_out;

  u32* MD     = (u32*)d_ws;                       // 64 KB packed (Bm-C | Dm)
  float* sTf  = (float*)((char*)d_ws + 65536);    // 64 KB (A+C) f-major
  float* uall = (float*)((char*)d_ws + 131072);   // 1 MB u[B][128]
  int mode = 0;
  if (ws_size >= (size_t)131072 + (size_t)2048 * 128 * 4) mode = 2;
  else if (ws_size >= (size_t)131072)                     mode = 1;

  if (mode >= 1) pre_kernel<<<64, 256, 0, stream>>>(w1, MD, sTf);
  if (mode == 2) preU_kernel<<<2048, 128, 0, stream>>>(q, sTf, b1, uall);
  din_kernel<<<2048, 256, 0, stream>>>(q, keys, mask, w1, b1, pa, w2, b2,
                                       MD, uall, mode, out);
}